// Round 13
// baseline (100.610 us; speedup 1.0000x reference)
//
#include <hip/hip_runtime.h>

#define NS 65536
#define DD 32
#define RR 128
#define SPB 16            // samples per tile
#define STR 132           // padded LDS row stride (floats)
#define NT (NS / SPB)     // 4096 tiles
#define NBLK 1024         // persistent blocks: exactly 4/CU, 4 tiles each

typedef float f2 __attribute__((ext_vector_type(2)));

static __device__ __forceinline__ f2 pkfma(f2 a, f2 b, f2 c) {
    f2 d;
    asm("v_pk_fma_f32 %0, %1, %2, %3" : "=v"(d) : "v"(a), "v"(b), "v"(c));
    return d;
}

// neighbor-lane (xor 1) value via DPP quad_perm [1,0,3,2] — VALU pipe only.
static __device__ __forceinline__ float dpp_x1(float x) {
    return __int_as_float(__builtin_amdgcn_update_dpp(
        0, __float_as_int(x), 0xB1 /*quad_perm(1,0,3,2)*/, 0xF, 0xF, true));
}

// R17 = R16 (half-split lane pairs, SPB=16 — best, kernel ~40us) made 4-tile
// persistent at grid 1024 = exactly 4 blocks/CU, all co-resident.
// Why now (and why R10's persistence was neutral then): R10 ran at the OLD
// 2-waves/SIMD register wall, which masked prologue gains. R14 removed that
// wall; R16 showed residency beyond 16 waves/CU buys nothing. Remaining ~25us
// of stall at 16 waves/CU = per-generation serialization: 16 block
// generations/CU, each paying a cold param+X prologue (~1us exposed), a
// 4-barrier convoy, and launch churn. R17: params loaded+pinned ONCE per slot
// (16x -> 1x per CU); next tile's X prefetched to regs ~6us ahead (T14
// issue-early/write-late) and ds_written to LDS after the flush barrier; zero
// launch churn. Per-(sample,rule) arithmetic, reduction order, and phases
// byte-identical to R16 => absmax exactly 8.077936e-28.
// (256,4): budget 128 >= ~110 demand (px adds 4 regs) — no R8-style spill.
__global__ __launch_bounds__(256, 4) void anfis_main(
    const float* __restrict__ X, const float* __restrict__ A,
    const float* __restrict__ B, const float* __restrict__ C,
    float* __restrict__ out_pred, float* __restrict__ out_str,
    float* __restrict__ out_norm)
{
    __shared__ float SBUF[SPB * STR];   // strengths, row = sample-in-tile
    __shared__ float PBUF[SPB * STR];   // strength * rule_out
    __shared__ float XT[SPB * DD];      // current tile's X (2KB)
    __shared__ float pS[SPB][8];
    __shared__ float pD[SPB][8];
    __shared__ float scale_lds[SPB];

    const int tid   = threadIdx.x;
    const int rule  = tid >> 1;         // 0..127
    const int half  = tid & 1;          // dim-half: 0 -> dims 0-15, 1 -> 16-31
    const int xoff  = half * 16;
    const int bid   = blockIdx.x;

    // ---- stage tile-0 X to LDS (2KB, 1 float4 for first 128 threads) ----
    if (tid < 128)
        ((float4*)XT)[tid] = ((const float4*)(X + (size_t)bid * SPB * DD))[tid];

    // ---- per-thread HALF-rule params -> VGPR pairs (48 + 1 regs), ONCE ----
    f2 w01_[4], w23_[4], n01_[4], n23_[4], c01_[4], c23_[4];
    float biasv;
    {
        const float4* av = (const float4*)(A + rule * DD + xoff);
        const float4* bv = (const float4*)(B + rule * DD + xoff);
        const float*  cp = C + rule * (DD + 1) + xoff;
        #pragma unroll
        for (int i = 0; i < 4; ++i) {
            float4 va = av[i], vb = bv[i];
            float w0 = 0.8493218003f * __builtin_amdgcn_rcpf(fmaxf(vb.x, 1e-8f));
            float w1 = 0.8493218003f * __builtin_amdgcn_rcpf(fmaxf(vb.y, 1e-8f));
            float w2 = 0.8493218003f * __builtin_amdgcn_rcpf(fmaxf(vb.z, 1e-8f));
            float w3 = 0.8493218003f * __builtin_amdgcn_rcpf(fmaxf(vb.w, 1e-8f));
            w01_[i] = f2{w0, w1};            w23_[i] = f2{w2, w3};
            n01_[i] = f2{-va.x * w0, -va.y * w1};
            n23_[i] = f2{-va.z * w2, -va.w * w3};
            c01_[i] = f2{cp[4*i + 0], cp[4*i + 1]};
            c23_[i] = f2{cp[4*i + 2], cp[4*i + 3]};
        }
        biasv = half ? C[rule * (DD + 1) + DD] : 0.0f;  // bias lives in half 1
    }
    __syncthreads();                    // XT visible to all 4 waves

    // Pin params once: forbid rematerialization/reload across the tile loop.
    #pragma unroll
    for (int i = 0; i < 4; ++i)
        asm("" : "+v"(w01_[i]), "+v"(w23_[i]), "+v"(n01_[i]),
                 "+v"(n23_[i]), "+v"(c01_[i]), "+v"(c23_[i]));
    asm("" : "+v"(biasv));

    // prefetch tile-1's X into regs (issue-early; written to LDS write-late)
    float4 px;
    if (tid < 128)
        px = ((const float4*)(X + ((size_t)bid + NBLK) * SPB * DD))[tid];

    // parity-selected output row buffer: even lanes write strengths,
    // odd lanes write strength*rule_out — one non-divergent ds_write each.
    float* wbuf = half ? PBUF : SBUF;

    #define LOADQ(buf, jj) { _Pragma("unroll") \
        for (int g = 0; g < 4; ++g) \
            buf[g] = *(const float4*)&XT[(jj) * DD + xoff + g * 4]; }

    #define DOSAMPLE(buf, jj) { \
        f2 s01 = f2{0.f, 0.f}, s23 = f2{0.f, 0.f}; \
        f2 r01 = f2{biasv, 0.f}, r23 = f2{0.f, 0.f}; \
        _Pragma("unroll") \
        for (int g = 0; g < 4; ++g) { \
            const f2* xp2 = (const f2*)&buf[g]; \
            f2 x01 = xp2[0], x23 = xp2[1]; \
            f2 t01 = pkfma(x01, w01_[g], n01_[g]); \
            s01 = pkfma(t01, t01, s01); \
            r01 = pkfma(x01, c01_[g], r01); \
            f2 t23 = pkfma(x23, w23_[g], n23_[g]); \
            s23 = pkfma(t23, t23, s23); \
            r23 = pkfma(x23, c23_[g], r23); \
        } \
        float sh = (s01.x + s01.y) + (s23.x + s23.y); \
        float rh = (r01.x + r01.y) + (r23.x + r23.y); \
        float stot = sh + dpp_x1(sh); \
        float rtot = rh + dpp_x1(rh); \
        float st = __builtin_amdgcn_exp2f(-stot); \
        wbuf[(jj) * STR + rule] = half ? st * rtot : st; }

    #pragma unroll 1
    for (int t = 0; t < 4; ++t) {
        const int nbase = (bid + t * NBLK) * SPB;

        // ---- main loop: 16 samples, half-sample reg double-buffer ----
        float4 qa[4], qb[4];
        LOADQ(qa, 0)
        for (int j = 0; j < SPB; j += 2) {
            LOADQ(qb, j + 1)                    // prefetch j+1 while computing j
            DOSAMPLE(qa, j)
            if (j + 2 < SPB) LOADQ(qa, j + 2)   // prefetch j+2
            DOSAMPLE(qb, j + 1)
        }
        __syncthreads();        // S/P ready; all XT reads of this tile done

        // ---- per-sample sums: 16 samples x 8 octants = 128 threads ----
        if (tid < 128) {
            int s = tid >> 3, o = tid & 7;      // 16B-group o covers 16 floats
            const float4* srow = (const float4*)&SBUF[s * STR + o * 16];
            const float4* prow = (const float4*)&PBUF[s * STR + o * 16];
            float ss = 0.f, dd = 0.f;
            #pragma unroll
            for (int k = 0; k < 4; ++k) {
                float4 v = srow[k]; ss += (v.x + v.y) + (v.z + v.w);
                float4 p = prow[k]; dd += (p.x + p.y) + (p.z + p.w);
            }
            pS[s][o] = ss; pD[s][o] = dd;
        }
        __syncthreads();
        float predv = 0.f;
        if (tid < SPB) {
            float ss = 0.f, dd = 0.f;
            #pragma unroll
            for (int o = 0; o < 8; ++o) { ss += pS[tid][o]; dd += pD[tid][o]; }
            float sc = 1.0f / (ss + 1e-8f);
            predv = dd * sc;                // store deferred past the barrier
            scale_lds[tid] = sc;
        }
        __syncthreads();
        if (tid < SPB) out_pred[nbase + tid] = predv;

        // ---- flush strengths + normalized, float4-coalesced ----
        #pragma unroll
        for (int it = 0; it < 2; ++it) {
            int f   = it * 256 + tid;       // float4 index over 16x32 tile
            int row = f >> 5;
            int col = f & 31;
            float4 v = *(const float4*)&SBUF[row * STR + col * 4];
            float sc = scale_lds[row];
            size_t base = ((size_t)(nbase + row)) * RR + col * 4;
            *(float4*)(out_str  + base) = v;
            *(float4*)(out_norm + base) = make_float4(v.x * sc, v.y * sc, v.z * sc, v.w * sc);
        }

        if (t < 3) {
            // write-late: install next tile's X (reads done since barrier 1)
            if (tid < 128) ((float4*)XT)[tid] = px;
            __syncthreads();    // XT ready; SBUF flush reads also complete
            if (t < 2 && tid < 128)   // issue-early: prefetch tile t+2
                px = ((const float4*)(X +
                        ((size_t)bid + (t + 2) * NBLK) * SPB * DD))[tid];
        }
    }
    #undef LOADQ
    #undef DOSAMPLE
}

extern "C" void kernel_launch(void* const* d_in, const int* in_sizes, int n_in,
                              void* d_out, int out_size, void* d_ws, size_t ws_size,
                              hipStream_t stream) {
    const float* X = (const float*)d_in[0];
    const float* A = (const float*)d_in[1];
    const float* B = (const float*)d_in[2];
    const float* C = (const float*)d_in[3];

    float* pred = (float*)d_out;
    float* str  = pred + NS;
    float* nrm  = str + (size_t)NS * RR;

    anfis_main<<<dim3(NBLK), dim3(256), 0, stream>>>(X, A, B, C, pred, str, nrm);
}